// Round 6
// baseline (196.639 us; speedup 1.0000x reference)
//
#include <hip/hip_runtime.h>
#include <math.h>

#define B 2
#define C 32
#define H 128
#define W 416
#define D 48
#define HW (H*W)
#define CHW (C*HW)
#define EPSN 1e-3f
#define ISCALE 0.05892556509887896f   // 1/sqrt(C*9)
#define LSTRH 40                       // LDS column stride in halves: 80B -> 16B-aligned cols
#define NDSP 4                         // d-split factor
#define DSPL (D / NDSP)                // 12 disparities per block

typedef _Float16 half2v __attribute__((ext_vector_type(2)));
typedef _Float16 half4v __attribute__((ext_vector_type(4)));
typedef _Float16 half8v __attribute__((ext_vector_type(8)));

#if defined(__has_builtin)
#if __has_builtin(__builtin_amdgcn_fdot2)
#define FDOT2(a, b, c) __builtin_amdgcn_fdot2((a), (b), (c), false)
#endif
#endif
#ifndef FDOT2
#define FDOT2(a, b, c) ((c) + (float)(a)[0] * (float)(b)[0] + (float)(a)[1] * (float)(b)[1])
#endif

__device__ __forceinline__ float clip10(float x) {
    return fminf(fmaxf(x, -10.0f), 10.0f);
}

// ---------------------------------------------------------------------------
// k_sq: per-pixel sum over channels of squares for xl/xr; inverse norm for xm.
__global__ __launch_bounds__(256) void k_sq(const float* __restrict__ xl,
                                            const float* __restrict__ xr,
                                            const float* __restrict__ xm,
                                            float* __restrict__ sql,
                                            float* __restrict__ sqr,
                                            float* __restrict__ inm) {
    int idx = blockIdx.x * 256 + threadIdx.x;   // [0, B*HW)
    if (idx >= B * HW) return;
    int b = idx / HW, hw = idx - b * HW;
    const float* pl = xl + (size_t)b * CHW + hw;
    const float* pr = xr + (size_t)b * CHW + hw;
    const float* pm = xm + (size_t)b * CHW + hw;
    float al = 0.f, ar = 0.f, am = 0.f;
#pragma unroll
    for (int c = 0; c < C; ++c) {
        float vl = pl[c * HW], vr = pr[c * HW], vm = pm[c * HW];
        al += vl * vl; ar += vr * vr; am += vm * vm;
    }
    sql[idx] = al;
    sqr[idx] = ar;
    inm[idx] = 1.0f / fmaxf(sqrtf(am), EPSN);
}

// ---------------------------------------------------------------------------
// k_norm: 3x3 zero-padded box of sql/sqr -> inverse patch norms inl/inr.
__global__ __launch_bounds__(256) void k_norm(const float* __restrict__ sql,
                                              const float* __restrict__ sqr,
                                              float* __restrict__ inl,
                                              float* __restrict__ inr) {
    int idx = blockIdx.x * 256 + threadIdx.x;
    if (idx >= B * HW) return;
    int b = idx / HW, hw = idx - b * HW;
    int h = hw / W, w = hw - h * W;
    float sl = 0.f, sr = 0.f;
#pragma unroll
    for (int di = -1; di <= 1; ++di) {
        int hh = h + di;
        if (hh < 0 || hh >= H) continue;
#pragma unroll
        for (int dj = -1; dj <= 1; ++dj) {
            int ww = w + dj;
            if (ww < 0 || ww >= W) continue;
            int p = b * HW + hh * W + ww;
            sl += sql[p];
            sr += sqr[p];
        }
    }
    inl[idx] = 1.0f / fmaxf(sqrtf(sl), EPSN);
    inr[idx] = 1.0f / fmaxf(sqrtf(sr), EPSN);
}

// ---------------------------------------------------------------------------
// k_box: per-channel 3x3 zero-padded box sums, 4 outputs/thread, f16 output.
__global__ __launch_bounds__(256) void k_box(const float* __restrict__ xl,
                                             const float* __restrict__ xr,
                                             _Float16* __restrict__ boxl,
                                             _Float16* __restrict__ boxr) {
    int idx = blockIdx.x * 256 + threadIdx.x;   // [0, B*C*H*W/4)
    int w4 = (idx % (W / 4)) * 4;
    int h = (idx / (W / 4)) % H;
    int rest = idx / (H * (W / 4));             // b*C + c
    size_t base = (size_t)rest * HW;
    float4 al = {0.f, 0.f, 0.f, 0.f}, ar = {0.f, 0.f, 0.f, 0.f};
#pragma unroll
    for (int dh = -1; dh <= 1; ++dh) {
        int hh = h + dh;
        if (hh < 0 || hh >= H) continue;
        const float* rl = xl + base + hh * W;
        const float* rr = xr + base + hh * W;
        float4 m = *(const float4*)(rl + w4);
        float lm = (w4 > 0) ? rl[w4 - 1] : 0.f;
        float rm = (w4 + 4 < W) ? rl[w4 + 4] : 0.f;
        al.x += lm + m.x + m.y;  al.y += m.x + m.y + m.z;
        al.z += m.y + m.z + m.w; al.w += m.z + m.w + rm;
        float4 n = *(const float4*)(rr + w4);
        float ln = (w4 > 0) ? rr[w4 - 1] : 0.f;
        float rn = (w4 + 4 < W) ? rr[w4 + 4] : 0.f;
        ar.x += ln + n.x + n.y;  ar.y += n.x + n.y + n.z;
        ar.z += n.y + n.z + n.w; ar.w += n.z + n.w + rn;
    }
    half4v ol = {(_Float16)al.x, (_Float16)al.y, (_Float16)al.z, (_Float16)al.w};
    half4v orr = {(_Float16)ar.x, (_Float16)ar.y, (_Float16)ar.z, (_Float16)ar.w};
    *(half4v*)(boxl + base + h * W + w4) = ol;
    *(half4v*)(boxr + base + h * W + w4) = orr;
}

// ---------------------------------------------------------------------------
// stage_row_h: stage [C][W] f16 row into LDS transposed [w][c], stride LSTRH.
// Lane map t=[g|cl(3b)|rw(3b)]: write banks (16rw+20k+4ch+cl/2)%32 -> all 32
// banks, 2 lanes/bank (free). Global: 8B/lane, 64B segments.
__device__ __forceinline__ void stage_row_h(const _Float16* __restrict__ gsrc,
                                            _Float16* __restrict__ lds,
                                            int tid, int nthreads) {
    for (int t = tid; t < (W / 4) * C; t += nthreads) {
        int rw = t & 7;
        int cl = (t >> 3) & 7;
        int g  = t >> 6;              // 0..51
        int wg = g % 13;
        int ch = g / 13;              // 0..3
        int c  = ch * 8 + cl;
        int w4 = (wg * 8 + rw) * 4;
        half4v v = *(const half4v*)(gsrc + (size_t)c * HW + w4);
        lds[(w4 + 0) * LSTRH + c] = v[0];
        lds[(w4 + 1) * LSTRH + c] = v[1];
        lds[(w4 + 2) * LSTRH + c] = v[2];
        lds[(w4 + 3) * LSTRH + c] = v[3];
    }
}

// same but f32 source with convert-on-stage
__device__ __forceinline__ void stage_row_cvt(const float* __restrict__ gsrc,
                                              _Float16* __restrict__ lds,
                                              int tid, int nthreads) {
    for (int t = tid; t < (W / 4) * C; t += nthreads) {
        int rw = t & 7;
        int cl = (t >> 3) & 7;
        int g  = t >> 6;
        int wg = g % 13;
        int ch = g / 13;
        int c  = ch * 8 + cl;
        int w4 = (wg * 8 + rw) * 4;
        float4 v = *(const float4*)(gsrc + (size_t)c * HW + w4);
        lds[(w4 + 0) * LSTRH + c] = (_Float16)v.x;
        lds[(w4 + 1) * LSTRH + c] = (_Float16)v.y;
        lds[(w4 + 2) * LSTRH + c] = (_Float16)v.z;
        lds[(w4 + 3) * LSTRH + c] = (_Float16)v.w;
    }
}

// dot over 32 channels: col is 16B-aligned LDS column (32 f16 = 4 b128)
__device__ __forceinline__ float dot16(const half2v* __restrict__ a,
                                       const _Float16* __restrict__ col) {
    const half8v* c8 = (const half8v*)col;
    float s = 0.f;
#pragma unroll
    for (int q = 0; q < 4; ++q) {
        half8v v = c8[q];
#pragma unroll
        for (int i = 0; i < 4; ++i) {
            half2v p = {v[2 * i], v[2 * i + 1]};
            s = FDOT2(a[4 * q + i], p, s);
        }
    }
    return s;
}

// one column read -> two dots
__device__ __forceinline__ void dot16x2(const half2v* __restrict__ a0,
                                        const half2v* __restrict__ a1,
                                        const _Float16* __restrict__ col,
                                        float& r0, float& r1) {
    const half8v* c8 = (const half8v*)col;
    float s0 = 0.f, s1 = 0.f;
#pragma unroll
    for (int q = 0; q < 4; ++q) {
        half8v v = c8[q];
#pragma unroll
        for (int i = 0; i < 4; ++i) {
            half2v p = {v[2 * i], v[2 * i + 1]};
            s0 = FDOT2(a0[4 * q + i], p, s0);
            s1 = FDOT2(a1[4 * q + i], p, s1);
        }
    }
    r0 = s0; r1 = s1;
}

// ---------------------------------------------------------------------------
// k_lr: sL and sR. One block per (b,h,dc); DSPL=12 d's each -> 1024 blocks,
// 4 blocks/CU (LDS 35KB). 2-w register tiling, f16 fragments, rolling store.
__global__ __launch_bounds__(256) void k_lr(const float* __restrict__ xm,
                                            const _Float16* __restrict__ boxl,
                                            const _Float16* __restrict__ boxr,
                                            const float* __restrict__ inl,
                                            const float* __restrict__ inr,
                                            const float* __restrict__ inm,
                                            float* __restrict__ out) {
    __shared__ _Float16 sB[W * LSTRH];   // 33280 B
    __shared__ float sIn[W];
    int tid = threadIdx.x;
    int h = blockIdx.x;
    int b = blockIdx.y;
    int d0 = blockIdx.z * DSPL;
    bool act = tid < (W / 2);            // 208 pairs
    int w = 2 * tid;
    int bhw = b * HW + h * W;
    const float* pm = xm + (size_t)b * CHW + h * W;

    half2v fl0[C / 2], fl1[C / 2];
    if (act) {
        float2 im = *(const float2*)(inm + bhw + w);
#pragma unroll
        for (int c2 = 0; c2 < C / 2; ++c2) {
            float2 ma = *(const float2*)(pm + (2 * c2) * HW + w);
            float2 mb = *(const float2*)(pm + (2 * c2 + 1) * HW + w);
            half2v f0 = {(_Float16)(ma.x * im.x), (_Float16)(mb.x * im.x)};
            half2v f1 = {(_Float16)(ma.y * im.y), (_Float16)(mb.y * im.y)};
            fl0[c2] = f0; fl1[c2] = f1;
        }
    } else {
#pragma unroll
        for (int c2 = 0; c2 < C / 2; ++c2) {
            half2v z = {(_Float16)0.f, (_Float16)0.f};
            fl0[c2] = z; fl1[c2] = z;
        }
    }

    // ---- phase L: cols v = w+d0+j; store d=d0+j-1 at iter j ----
    stage_row_h(boxl + (size_t)b * CHW + h * W, sB, tid, 256);
    for (int j = tid; j < W; j += 256) sIn[j] = inl[bhw + j];
    __syncthreads();
    if (act) {
        float* o = out + ((size_t)b * 3 + 0) * D * HW + h * W;
        float a0p = 0.f;
#pragma unroll 4
        for (int j = 0; j <= DSPL; ++j) {
            int v = w + d0 + j;
            float a0 = 0.f, a1 = 0.f;
            if (v < W) {
                dot16x2(fl0, fl1, sB + v * LSTRH, a0, a1);
                float s = sIn[v] * ISCALE;
                a0 = clip10(a0 * s);
                a1 = clip10(a1 * s);
            }
            if (j >= 1) {
                int d = d0 + j - 1;
                *(float2*)(o + (size_t)d * HW + w) = make_float2(a0p, a1);
            }
            a0p = a0;
        }
    }
    __syncthreads();

    // ---- phase R: cols v = w-d0-(DSPL-1)+j; store d=d0+DSPL-j at iter j ----
    stage_row_h(boxr + (size_t)b * CHW + h * W, sB, tid, 256);
    for (int j = tid; j < W; j += 256) sIn[j] = inr[bhw + j];
    __syncthreads();
    if (act) {
        float* o = out + ((size_t)b * 3 + 1) * D * HW + h * W;
        float a0p = 0.f;
#pragma unroll 4
        for (int j = 0; j <= DSPL; ++j) {
            int v = w - d0 - (DSPL - 1) + j;
            float a0 = 0.f, a1 = 0.f;
            if (v >= 0) {
                dot16x2(fl0, fl1, sB + v * LSTRH, a0, a1);
                float s = sIn[v] * ISCALE;
                a0 = clip10(a0 * s);
                a1 = clip10(a1 * s);
            }
            if (j >= 1) {
                int d = d0 + DSPL - j;
                *(float2*)(o + (size_t)d * HW + w) = make_float2(a0p, a1);
            }
            a0p = a0;
        }
    }
}

// ---------------------------------------------------------------------------
// k_e: EH[b,d,h,v] = horizontal 3-tap of E, E[v] = sum_c xl[.,v+2d]*xr[.,v].
// Wave-halo shuffles; f16 LDS tile; DSPL=12 -> 1024 blocks, 4/CU.
__global__ __launch_bounds__(448) void k_e(const float* __restrict__ xl,
                                           const float* __restrict__ xr,
                                           float* __restrict__ EH) {
    __shared__ _Float16 sXL[W * LSTRH];  // 33280 B
    int tid = threadIdx.x;
    int h = blockIdx.x;
    int b = blockIdx.y;
    int d0 = blockIdx.z * DSPL;
    int lane = tid & 63;
    int wv = tid >> 6;                // 0..6
    int v = wv * 62 + lane - 1;       // -1 .. 433
    bool vin = (v >= 0) && (v < W);
    const float* br = xr + (size_t)b * CHW + h * W;

    half2v xrv[C / 2];
#pragma unroll
    for (int c2 = 0; c2 < C / 2; ++c2) {
        float va = vin ? br[(2 * c2) * HW + v] : 0.f;
        float vb = vin ? br[(2 * c2 + 1) * HW + v] : 0.f;
        half2v x = {(_Float16)va, (_Float16)vb};
        xrv[c2] = x;
    }

    stage_row_cvt(xl + (size_t)b * CHW + h * W, sXL, tid, 448);
    __syncthreads();

    bool wr = (lane >= 1) && (lane <= 62) && (v < W);   // v>=0 implied
    float* pe = EH + (((size_t)b * D) * H + h) * W + v;
    for (int d = d0; d < d0 + DSPL; ++d) {
        int s = 2 * d;
        float e = 0.0f;
        if (vin && v + s < W) e = dot16(xrv, sXL + (v + s) * LSTRH);
        float em = __shfl_up(e, 1);
        float ep = __shfl_down(e, 1);
        float eh = em + e + ep;
        if (wr) pe[(size_t)d * HW] = eh;
    }
}

// ---------------------------------------------------------------------------
// k_lr2: sLR = vertical 3-tap of EH at column vc=w-d, times inverse norms.
#define DCH 12
__global__ __launch_bounds__(448) void k_lr2(const float* __restrict__ EH,
                                             const float* __restrict__ inl,
                                             const float* __restrict__ inr,
                                             float* __restrict__ out) {
    int w = threadIdx.x;
    int dc = blockIdx.x;              // 0..3
    int h = blockIdx.y;
    int b = blockIdx.z;
    if (w >= W) return;
    int bhw = b * HW + h * W;
    bool hm = (h > 0), hp = (h < H - 1);

    float* o = out + ((size_t)b * 3 + 2) * D * HW + h * W + w;
#pragma unroll
    for (int i = 0; i < DCH; ++i) {
        int d = dc * DCH + i;
        float r = 0.0f;
        if (w >= d && w + d < W) {
            int vc = w - d;
            const float* base = EH + ((size_t)b * D + d) * HW + vc;
            float e = base[h * W];
            if (hm) e += base[(h - 1) * W];
            if (hp) e += base[(h + 1) * W];
            float nl = inl[bhw + w + d];
            float nr = inr[bhw + vc];
            r = clip10(e * nl * nr * ISCALE);
        }
        o[(size_t)d * HW] = r;
    }
}

// ---------------------------------------------------------------------------
extern "C" void kernel_launch(void* const* d_in, const int* in_sizes, int n_in,
                              void* d_out, int out_size, void* d_ws, size_t ws_size,
                              hipStream_t stream) {
    const float* xl = (const float*)d_in[0];
    const float* xm = (const float*)d_in[1];
    const float* xr = (const float*)d_in[2];
    float* out = (float*)d_out;

    // fp32 region first, then f16 boxes
    float* ws = (float*)d_ws;
    float* EH   = ws;                              // B*D*H*W fp32
    float* inl  = EH + (size_t)B * D * HW;         // B*HW
    float* inr  = inl + B * HW;
    float* inm  = inr + B * HW;
    float* sql  = inm + B * HW;
    float* sqr  = sql + B * HW;
    _Float16* boxl = (_Float16*)(sqr + B * HW);    // B*C*H*W f16
    _Float16* boxr = boxl + (size_t)B * CHW;

    k_sq<<<dim3((B * HW + 255) / 256), dim3(256), 0, stream>>>(xl, xr, xm, sql, sqr, inm);
    k_norm<<<dim3((B * HW + 255) / 256), dim3(256), 0, stream>>>(sql, sqr, inl, inr);
    k_box<<<dim3((B * CHW / 4 + 255) / 256), dim3(256), 0, stream>>>(xl, xr, boxl, boxr);
    k_e<<<dim3(H, B, NDSP), dim3(448), 0, stream>>>(xl, xr, EH);
    k_lr<<<dim3(H, B, NDSP), dim3(256), 0, stream>>>(xm, boxl, boxr, inl, inr, inm, out);
    k_lr2<<<dim3(4, H, B), dim3(448), 0, stream>>>(EH, inl, inr, out);
}